// Round 3
// baseline (313.429 us; speedup 1.0000x reference)
//
#include <hip/hip_runtime.h>
#include <hip/hip_bf16.h>
#include <math.h>

#define D_MODEL 1024
#define N_HEADS 16
#define D_K 64
#define N_CLASSES 32
#define S_LEN 16
#define BATCH 32
#define T_LEN 512

typedef __bf16 bf16_t;
typedef bf16_t bf16x8 __attribute__((ext_vector_type(8)));
typedef float f32x4 __attribute__((ext_vector_type(4)));
typedef long lx2 __attribute__((ext_vector_type(2)));

__device__ inline unsigned short f2bf(float f) {
    unsigned int u = __float_as_uint(f);
    unsigned int r = (u + 0x7FFFu + ((u >> 16) & 1u)) >> 16;   // RNE
    return (unsigned short)r;
}
// fast tanh: (e-1)/(e+1), e = exp(2x). Valid for |x| < 40. rel err ~1e-6.
__device__ inline float fast_tanh(float x) {
    float e = __expf(2.0f * x);
    return (e - 1.0f) * __builtin_amdgcn_rcpf(e + 1.0f);
}
__device__ inline float4 fast_tanh4(float4 v) {
    return make_float4(fast_tanh(v.x), fast_tanh(v.y), fast_tanh(v.z), fast_tanh(v.w));
}
__device__ inline float dot4(float4 a, float4 b) {
    return a.x * b.x + a.y * b.y + a.z * b.z + a.w * b.w;
}
// pack 4 floats -> 4 e4m3 bytes (OCP, HW cvt)
__device__ inline int pack_fp8x4(float4 v) {
    int p = __builtin_amdgcn_cvt_pk_fp8_f32(v.x, v.y, 0, false);
    p = __builtin_amdgcn_cvt_pk_fp8_f32(v.z, v.w, p, true);
    return p;
}

// async global->LDS, 16 bytes per lane (global_load_lds_dwordx4)
__device__ inline void async16(void* lds, const void* g) {
    __builtin_amdgcn_global_load_lds(
        (const __attribute__((address_space(1))) unsigned int*)g,
        (__attribute__((address_space(3))) unsigned int*)lds, 16, 0, 0);
}

// ================= prep: wql ∥ fp8-swizzle cvt (H,WK) ∥ bf16 cvt (Q,WQ) =====
// Launch-merge of 3 independent producers (10->4 dispatch plan). Roles by
// blockIdx range; wql blocks FIRST so the latency-bound 16-block role starts
// immediately and hides under the 17408-block cvt.
// fp8 swizzled layout (unchanged from prior rounds): for each 16-row x 64-byte
// subtile (rb,kb), a 1024B block at ((rb*16+kb)*1024); byte (quad*16+l16)*16 +
// kh*8 + b0 holds src[rb*16+l16][kb*64+kh*32+quad*8+b0]. Staging waves read
// lane-linear 1024B blocks; each MFMA lane reads its K=64 fragment as ONE
// conflict-free ds_read_b128 at lane*16.
__global__ __launch_bounds__(256) void prep_kernel(
    const float* __restrict__ H, int* __restrict__ Hf8,
    const float* __restrict__ WK, int* __restrict__ WKf8,
    const float4* __restrict__ Q, ushort4* __restrict__ Qb,
    const float4* __restrict__ WQ, ushort4* __restrict__ WQb,
    const float* __restrict__ ql, const float* __restrict__ WV,
    unsigned short* __restrict__ wqlb16)
{
    const int bid = blockIdx.x;
    const int tid = threadIdx.x;
    if (bid < 16) {
        // wql role: wqlb16[c][n] = bf16(sum_k ql[c][k] * WV[n][k]), full-K,
        // no LDS / no atomics / no memset; bf16 written directly.
        const int n0 = bid * 64;
        const int n = tid & 63;
        const int c0 = (tid >> 6) * 8;
        const float* wvp = WV + (size_t)(n0 + n) * D_MODEL;
        float acc[8] = {};
        for (int k = 0; k < 1024; k += 4) {
            const float4 wv = *(const float4*)(wvp + k);
#pragma unroll
            for (int c = 0; c < 8; c++) {
                const float4 qv = *(const float4*)(ql + (size_t)(c0 + c) * D_MODEL + k);
                acc[c] += dot4(qv, wv);
            }
        }
#pragma unroll
        for (int c = 0; c < 8; c++)
            wqlb16[(size_t)(c0 + c) * D_MODEL + n0 + n] = f2bf(acc[c]);
    } else if (bid < 17424) {
        // fp8 swizzled cvt: A = H (4194304 words, scale 1), B = WK (262144, x512
        // -- N(0,1e-3) would be subnormal in e4m3)
        int i = (bid - 16) * 256 + tid;
        const float* in; int* out; float s;
        if (i < 4194304) { in = H; out = Hf8; s = 1.0f; }
        else { i -= 4194304; in = WK; out = WKf8; s = 512.0f; }
        const int p = i << 2;             // byte index in swizzled output
        const int blk = p >> 10;
        const int pos = p & 1023;
        const int rb = blk >> 4, kb = blk & 15;
        const int q = pos >> 4;
        const int quad = q >> 4, l16 = q & 15;
        const int o = pos & 15;
        const int kh = o >> 3, b0 = o & 7;
        const int r = rb * 16 + l16;
        const int k = kb * 64 + kh * 32 + quad * 8 + b0;
        float4 v = *(const float4*)(in + (size_t)r * 1024 + k);
        v.x *= s; v.y *= s; v.z *= s; v.w *= s;
        out[i] = pack_fp8x4(v);
    } else {
        // bf16 cvt: A = Q (131072 float4), B = WQ (262144 float4)
        int i = (bid - 17424) * 256 + tid;
        const float4* in; ushort4* out;
        if (i < 131072) { in = Q + i; out = Qb + i; }
        else { i -= 131072; in = WQ + i; out = WQb + i; }
        float4 v = *in;
        ushort4 o;
        o.x = f2bf(v.x); o.y = f2bf(v.y); o.z = f2bf(v.z); o.w = f2bf(v.w);
        *out = o;
    }
}

// ================= gemms: fp8 GEMM ∥ qproj bf16 GEMM ∥ kv GEMM ==============
// All three depend only on prep outputs / raw inputs; disjoint writes.
// Union LDS = 33280 B (kv role) -> fp8 role still 4 blocks/CU (VGPR-capped
// at 4 waves/SIMD anyway, and 160K/33.3K = 4.8 LDS-wise): no occupancy loss.
__global__ __launch_bounds__(256) void gemms_kernel(
    const unsigned char* __restrict__ A8, const unsigned char* __restrict__ B8,
    unsigned short* __restrict__ wkt_b,
    const unsigned short* __restrict__ Qb, const unsigned short* __restrict__ WQb,
    unsigned short* __restrict__ qproj_b,
    const float* __restrict__ H, const unsigned short* __restrict__ wql16,
    float* __restrict__ kv)
{
    __shared__ __align__(16) char smem[33280];
    const int bid = blockIdx.x;
    const int tid = threadIdx.x;
    const int wid = tid >> 6;
    const int lane = tid & 63;
    const int quad = lane >> 4;
    const int l16 = lane & 15;

    if (bid < 1024) {
        // ---- fp8 GEMM: wkt = bf16(fast_tanh((H8 @ WK8^T)/512)), 16384x1024 ---
        unsigned char* As = (unsigned char*)smem;          // 8 KB
        unsigned char* Bs = (unsigned char*)smem + 8192;   // 8 KB
        const int m0 = (bid & 127) * 128;   // m-fast grid (old dim3(128,8))
        const int n0 = (bid >> 7) * 128;
        const int wm = (wid >> 1) * 64;
        const int wn = (wid & 1) * 64;
        const int stA = wm >> 4;
        const int stB = wn >> 4;
        const int st = wid;
        const int cl = lane * 16;

        f32x4 acc[4][4] = {};
        const unsigned char* Ab = A8 + ((size_t)(m0 >> 4) * 16) * 1024;
        const unsigned char* Bb = B8 + ((size_t)(n0 >> 4) * 16) * 1024;

        for (int kb = 0; kb < 16; kb++) {
            async16(&As[tid * 16],        Ab + ((size_t)st * 16 + kb) * 1024 + cl);
            async16(&As[4096 + tid * 16], Ab + ((size_t)(st + 4) * 16 + kb) * 1024 + cl);
            async16(&Bs[tid * 16],        Bb + ((size_t)st * 16 + kb) * 1024 + cl);
            async16(&Bs[4096 + tid * 16], Bb + ((size_t)(st + 4) * 16 + kb) * 1024 + cl);
            __syncthreads();

            lx2 a8[4], b8[4];
#pragma unroll
            for (int mt = 0; mt < 4; mt++)
                a8[mt] = *(const lx2*)&As[(stA + mt) * 1024 + lane * 16];
#pragma unroll
            for (int nt = 0; nt < 4; nt++)
                b8[nt] = *(const lx2*)&Bs[(stB + nt) * 1024 + lane * 16];
#pragma unroll
            for (int mt = 0; mt < 4; mt++)
#pragma unroll
                for (int nt = 0; nt < 4; nt++) {
                    acc[mt][nt] = __builtin_amdgcn_mfma_f32_16x16x32_fp8_fp8(
                        a8[mt].x, b8[nt].x, acc[mt][nt], 0, 0, 0);
                    acc[mt][nt] = __builtin_amdgcn_mfma_f32_16x16x32_fp8_fp8(
                        a8[mt].y, b8[nt].y, acc[mt][nt], 0, 0, 0);
                }
            __syncthreads();
        }

#pragma unroll
        for (int mt = 0; mt < 4; mt++)
#pragma unroll
            for (int nt = 0; nt < 4; nt++)
#pragma unroll
                for (int r = 0; r < 4; r++) {
                    const int row = m0 + wm + mt * 16 + quad * 4 + r;
                    const int col = n0 + wn + nt * 16 + l16;
                    wkt_b[(size_t)row * 1024 + col] =
                        f2bf(fast_tanh(acc[mt][nt][r] * (1.0f / 512.0f)));
                }
    } else if (bid < 1056) {
        // ---- qproj bf16 GEMM: qproj = Qb @ WQb^T (512 x 1024, K=1024) -------
        unsigned short* As = (unsigned short*)smem;            // 8 KB
        unsigned short* Bs = (unsigned short*)(smem + 8192);   // 8 KB
        const int q = bid - 1024;
        const int m0 = (q & 3) * 128;
        const int n0 = (q >> 2) * 128;
        const int wm = (wid >> 1) * 64;
        const int wn = (wid & 1) * 64;

        f32x4 acc[4][4] = {};
        const int r0 = tid >> 2;
        const int cc0 = (tid & 3) * 8;

        for (int k0 = 0; k0 < 1024; k0 += 32) {
            async16(&As[tid * 8],        Qb  + (size_t)(m0 + r0) * 1024 + k0 + cc0);
            async16(&As[2048 + tid * 8], Qb  + (size_t)(m0 + 64 + r0) * 1024 + k0 + cc0);
            async16(&Bs[tid * 8],        WQb + (size_t)(n0 + r0) * 1024 + k0 + cc0);
            async16(&Bs[2048 + tid * 8], WQb + (size_t)(n0 + 64 + r0) * 1024 + k0 + cc0);
            __syncthreads();

            bf16x8 af[4], bfr[4];
#pragma unroll
            for (int mt = 0; mt < 4; mt++)
                af[mt] = *(const bf16x8*)&As[(wm + mt * 16 + l16) * 32 + quad * 8];
#pragma unroll
            for (int nt = 0; nt < 4; nt++)
                bfr[nt] = *(const bf16x8*)&Bs[(wn + nt * 16 + l16) * 32 + quad * 8];
#pragma unroll
            for (int mt = 0; mt < 4; mt++)
#pragma unroll
                for (int nt = 0; nt < 4; nt++)
                    acc[mt][nt] = __builtin_amdgcn_mfma_f32_16x16x32_bf16(
                        af[mt], bfr[nt], acc[mt][nt], 0, 0, 0);
            __syncthreads();
        }

#pragma unroll
        for (int mt = 0; mt < 4; mt++)
#pragma unroll
            for (int nt = 0; nt < 4; nt++)
#pragma unroll
                for (int r = 0; r < 4; r++) {
                    const int row = m0 + wm + mt * 16 + quad * 4 + r;
                    const int col = n0 + wn + nt * 16 + l16;
                    qproj_b[(size_t)row * 1024 + col] = f2bf(acc[mt][nt][r]);
                }
    } else {
        // ---- kv GEMM: kv[((b*16+z)*32+c)*512+t] = sum_h tanh(H)*wql --------
        unsigned short* Ks = (unsigned short*)smem;             // 16 KB [tl][h]
        float* kvt = (float*)(smem + 16384);                    // 16.9 KB [tl][c] pad
        const int q = bid - 1056;
        const int chunk = q & 127;
        const int z = q >> 7;
        const int b = chunk >> 2;
        const int t0 = (chunk & 3) * 128;

#pragma unroll
        for (int it = 0; it < 8; it++) {
            const int idx = it * 256 + tid;
            const int row = idx >> 4;
            const int c4 = (idx & 15) * 4;
            float4 v = *(const float4*)(H + ((size_t)b * T_LEN + t0 + row) * D_MODEL + z * D_K + c4);
            v = fast_tanh4(v);
            ushort4 o;
            o.x = f2bf(v.x); o.y = f2bf(v.y); o.z = f2bf(v.z); o.w = f2bf(v.w);
            *(ushort4*)&Ks[row * 64 + c4] = o;
        }
        bf16x8 bfr[2][2];
#pragma unroll
        for (int ct = 0; ct < 2; ct++)
#pragma unroll
            for (int kh = 0; kh < 2; kh++)
                bfr[ct][kh] = *(const bf16x8*)(wql16 +
                    (size_t)(ct * 16 + l16) * D_MODEL + z * D_K + kh * 32 + quad * 8);
        __syncthreads();

        const int wt = wid * 32;
        f32x4 acc[2][2] = {};
#pragma unroll
        for (int tt = 0; tt < 2; tt++) {
            const bf16x8 a0 = *(const bf16x8*)&Ks[(wt + tt * 16 + l16) * 64 + quad * 8];
            const bf16x8 a1 = *(const bf16x8*)&Ks[(wt + tt * 16 + l16) * 64 + 32 + quad * 8];
#pragma unroll
            for (int ct = 0; ct < 2; ct++) {
                acc[tt][ct] = __builtin_amdgcn_mfma_f32_16x16x32_bf16(a0, bfr[ct][0], acc[tt][ct], 0, 0, 0);
                acc[tt][ct] = __builtin_amdgcn_mfma_f32_16x16x32_bf16(a1, bfr[ct][1], acc[tt][ct], 0, 0, 0);
            }
        }
#pragma unroll
        for (int tt = 0; tt < 2; tt++)
#pragma unroll
            for (int ct = 0; ct < 2; ct++)
#pragma unroll
                for (int r = 0; r < 4; r++)
                    kvt[(wt + tt * 16 + quad * 4 + r) * 33 + ct * 16 + l16] = acc[tt][ct][r];
        __syncthreads();

        float* outb = kv + (((size_t)b * 16 + z) * 32) * 512 + t0;
#pragma unroll
        for (int it = 0; it < 4; it++) {
            const int idx = it * 256 + tid;
            const int c = idx >> 5;
            const int tq = (idx & 31) * 4;
            float4 v = make_float4(kvt[(tq + 0) * 33 + c], kvt[(tq + 1) * 33 + c],
                                   kvt[(tq + 2) * 33 + c], kvt[(tq + 3) * 33 + c]);
            *(float4*)(outb + (size_t)c * 512 + tq) = v;
        }
    }
}

// ================= attn: block per (b,z), 8 waves x 4 c-tiles ===============
// 512 threads, 64 KB LDS, 2 blocks/CU (4 waves/SIMD, 80->~100 VGPR).
// v3 changes: (1) kv scalar loads software-pipelined (prefetch nt+1 into
// rotating regs -- the round-2 profile showed 2x occupancy bought only ~13%,
// so the residual stall is the per-iteration load->exp->fma chain);
// (2) MFMA cluster under s_setprio(1) (T5: attn-positive, m191);
// (3) race-free partial write per (b,c,z) -> no atomics, no d_out memset.
// Prefetch at nt=31 overreads <=256B past the kv slice -- lands in allocated
// workspace (WKf8 region at worst), loaded-but-unused.
__global__ __launch_bounds__(512, 4) void attn_mfma(
    const unsigned short* __restrict__ qproj, const unsigned short* __restrict__ wkt,
    const float* __restrict__ kv, float* __restrict__ part)
{
    __shared__ unsigned short wkts[512 * 64];   // 64 KB, [t][k] swizzled
    const int z = blockIdx.x;
    const int b = blockIdx.y;
    const int tid = threadIdx.x;
    const int wid = tid >> 6;                   // 0..7
    const int lane = tid & 63;
    const int quad = lane >> 4;
    const int l16 = lane & 15;

    const unsigned short* wb = wkt + (size_t)(b * T_LEN) * D_MODEL + z * D_K;
#pragma unroll
    for (int it = 0; it < 8; it++) {
        const int chunk = it * 512 + tid;
        const int row = chunk >> 3;     // t (0..511)
        const int c = chunk & 7;        // 16B chunk within 128B row
        // inverse-swizzled source: LDS(row,c) holds global chunk (c ^ (row&7))
        async16(&wkts[chunk * 8], wb + (size_t)row * D_MODEL + ((c ^ (row & 7)) * 8));
    }

    bf16x8 af[4][2];
#pragma unroll
    for (int ct = 0; ct < 4; ct++)
#pragma unroll
        for (int kh = 0; kh < 2; kh++)
            af[ct][kh] = *(const bf16x8*)(qproj +
                (size_t)((wid * 4 + ct) * 16 + l16) * D_MODEL + z * D_K + kh * 32 + quad * 8);
    __syncthreads();

    float den[4][4], num[4][4];
#pragma unroll
    for (int ct = 0; ct < 4; ct++)
#pragma unroll
        for (int r = 0; r < 4; r++) { den[ct][r] = 0.f; num[ct][r] = 0.f; }

    // per-lane kv base: kv[((b*16+z)*32 + wid*4 + ct)*512 + nt*16 + l16]
    const float* kvp = kv + (((size_t)b * 16 + z) * 32 + wid * 4) * 512 + l16;
    float kc[4];
#pragma unroll
    for (int ct = 0; ct < 4; ct++) kc[ct] = kvp[ct * 512];

    const int x0 = (quad ^ (l16 & 7)) * 8;        // swizzled read: chunks 0..3
    const int x1 = ((quad ^ 4) ^ (l16 & 7)) * 8;  // swizzled read: chunks 4..7
    for (int nt = 0; nt < 32; nt++) {
        float kn[4];
#pragma unroll
        for (int ct = 0; ct < 4; ct++) kn[ct] = kvp[ct * 512 + (nt + 1) * 16];
        const int rbase = (nt * 16 + l16) * 64;
        const bf16x8 b0 = *(const bf16x8*)&wkts[rbase + x0];
        const bf16x8 b1 = *(const bf16x8*)&wkts[rbase + x1];
        f32x4 a4[4];
        __builtin_amdgcn_s_setprio(1);
#pragma unroll
        for (int ct = 0; ct < 4; ct++) {
            f32x4 a = {};
            a = __builtin_amdgcn_mfma_f32_16x16x32_bf16(af[ct][0], b0, a, 0, 0, 0);
            a = __builtin_amdgcn_mfma_f32_16x16x32_bf16(af[ct][1], b1, a, 0, 0, 0);
            a4[ct] = a;
        }
        __builtin_amdgcn_s_setprio(0);
#pragma unroll
        for (int ct = 0; ct < 4; ct++)
#pragma unroll
            for (int r = 0; r < 4; r++) {
                const float e = __expf(a4[ct][r]);
                den[ct][r] += e;
                num[ct][r] += e * kc[ct];
            }
#pragma unroll
        for (int ct = 0; ct < 4; ct++) kc[ct] = kn[ct];
    }

#pragma unroll
    for (int ct = 0; ct < 4; ct++) {
        float s = 0.f;
#pragma unroll
        for (int r = 0; r < 4; r++) {
            float d = den[ct][r], n = num[ct][r];
#pragma unroll
            for (int off = 1; off < 16; off <<= 1) {
                d += __shfl_xor(d, off, 64);
                n += __shfl_xor(n, off, 64);
            }
            s += n / d;
        }
        s += __shfl_xor(s, 16, 64);
        s += __shfl_xor(s, 32, 64);
        if (lane == 0)
            part[((size_t)(b * N_CLASSES) + wid * 4 + ct) * 16 + z] = s;
    }
}

// ================= combine z + apply 1/16 s-mean: out[b,c] ==================
__global__ __launch_bounds__(256) void attn_reduce(
    const float* __restrict__ part, float* __restrict__ out)
{
    const int i = blockIdx.x * 256 + threadIdx.x;   // bc in [0,1024)
    const float* p = part + (size_t)i * 16;
    float s = 0.f;
#pragma unroll
    for (int zz = 0; zz < 16; zz++) s += p[zz];
    out[i] = s * (1.0f / 16.0f);
}

extern "C" void kernel_launch(void* const* d_in, const int* in_sizes, int n_in,
                              void* d_out, int out_size, void* d_ws, size_t ws_size,
                              hipStream_t stream)
{
    const float* Q  = (const float*)d_in[0];   // (32,16,1024)
    const float* H  = (const float*)d_in[1];   // (32,512,1024)
    const float* ql = (const float*)d_in[2];   // (32,1024)
    const float* WQ = (const float*)d_in[3];   // (1024,1024)
    const float* WK = (const float*)d_in[4];
    const float* WV = (const float*)d_in[5];
    float* out = (float*)d_out;                // (32,32)

    char* ws = (char*)d_ws;
    // Layout (peak 97 MB, same as prior rounds):
    //   0      .. 16.78MB : Hf8 (prep->gemms)
    //   24MB   .. 25MB    : Qb
    //   25MB   .. 27MB    : WQb
    //   27MB   .. 28MB    : qproj_b
    //   28MB   .. +64KB   : wqlb16
    //   29MB   .. +64KB   : part
    //   32MB   .. 65.5MB  : wkt_b
    //   64MB   .. 96MB    : kv
    //   96MB   .. 97MB    : WKf8
    unsigned char*  Hf8     = (unsigned char*)(ws);
    unsigned short* Qb      = (unsigned short*)(ws + (size_t)25165824);
    unsigned short* WQb     = (unsigned short*)(ws + (size_t)26214400);
    unsigned short* qproj_b = (unsigned short*)(ws + (size_t)28311552);
    unsigned short* wqlb16  = (unsigned short*)(ws + (size_t)29360128);
    float*          part    = (float*)(ws + (size_t)30408704);
    unsigned short* wkt_b   = (unsigned short*)(ws + (size_t)33554432);
    float*          kv      = (float*)(ws + (size_t)67108864);
    unsigned char*  WKf8    = (unsigned char*)(ws + (size_t)100663296);

    dim3 thr(256);
    // prep: wql (16) + fp8 cvt (17408) + bf16 cvt (1536) = 18960 blocks
    prep_kernel<<<dim3(18960), thr, 0, stream>>>(
        H, (int*)Hf8, WK, (int*)WKf8,
        (const float4*)Q, (ushort4*)Qb,
        (const float4*)WQ, (ushort4*)WQb,
        ql, WV, wqlb16);
    // gemms: fp8 wkt GEMM (1024) + qproj (32) + kv (2048) = 3104 blocks
    gemms_kernel<<<dim3(3104), thr, 0, stream>>>(
        Hf8, WKf8, wkt_b, Qb, WQb, qproj_b, H, wqlb16, kv);
    // fused scores -> exp -> num/den partials per (b,c,z)
    attn_mfma<<<dim3(16, 32), dim3(512), 0, stream>>>(qproj_b, wkt_b, kv, part);
    // combine z + 1/16 s-mean
    attn_reduce<<<dim3(4), thr, 0, stream>>>(part, out);
}

// Round 4
// 240.425 us; speedup vs baseline: 1.3036x; 1.3036x over previous
//
#include <hip/hip_runtime.h>
#include <hip/hip_bf16.h>
#include <math.h>

#define D_MODEL 1024
#define N_HEADS 16
#define D_K 64
#define N_CLASSES 32
#define S_LEN 16
#define BATCH 32
#define T_LEN 512

typedef __bf16 bf16_t;
typedef bf16_t bf16x8 __attribute__((ext_vector_type(8)));
typedef float f32x4 __attribute__((ext_vector_type(4)));
typedef long lx2 __attribute__((ext_vector_type(2)));

__device__ inline unsigned short f2bf(float f) {
    unsigned int u = __float_as_uint(f);
    unsigned int r = (u + 0x7FFFu + ((u >> 16) & 1u)) >> 16;   // RNE
    return (unsigned short)r;
}
// fast tanh: (e-1)/(e+1), e = exp(2x). Valid for |x| < 40. rel err ~1e-6.
__device__ inline float fast_tanh(float x) {
    float e = __expf(2.0f * x);
    return (e - 1.0f) * __builtin_amdgcn_rcpf(e + 1.0f);
}
__device__ inline float4 fast_tanh4(float4 v) {
    return make_float4(fast_tanh(v.x), fast_tanh(v.y), fast_tanh(v.z), fast_tanh(v.w));
}
__device__ inline float dot4(float4 a, float4 b) {
    return a.x * b.x + a.y * b.y + a.z * b.z + a.w * b.w;
}
// pack 4 floats -> 4 e4m3 bytes (OCP, HW cvt)
__device__ inline int pack_fp8x4(float4 v) {
    int p = __builtin_amdgcn_cvt_pk_fp8_f32(v.x, v.y, 0, false);
    p = __builtin_amdgcn_cvt_pk_fp8_f32(v.z, v.w, p, true);
    return p;
}

// async global->LDS, 16 bytes per lane (global_load_lds_dwordx4)
__device__ inline void async16(void* lds, const void* g) {
    __builtin_amdgcn_global_load_lds(
        (const __attribute__((address_space(1))) unsigned int*)g,
        (__attribute__((address_space(3))) unsigned int*)lds, 16, 0, 0);
}

// ---------------- fp32 -> fp8 e4m3, MFMA-FRAGMENT-SWIZZLED layout -----------
// Source: (R, 1024) fp32 row-major. Output: for each 16-row x 64-byte subtile
// (rb, kb), a 1024B block at ((rb*16 + kb)*1024) where byte position
// (quad*16+l16)*16 + kh*8 + b holds src[rb*16+l16][kb*64+kh*32+quad*8+b].
// => staging waves read lane-linear 1024B blocks (coalesced), and each MFMA
//    lane reads its whole K=64 fragment as ONE conflict-free ds_read_b128.
__global__ __launch_bounds__(256) void cvt2_fp8_sw(
    const float* __restrict__ inA, int* __restrict__ outA, int nA,
    const float* __restrict__ inB, int* __restrict__ outB, int nB, float sB)
{
    int i = blockIdx.x * 256 + threadIdx.x;
    const float* in;
    int* out;
    float s;
    if (i < nA) { in = inA; out = outA; s = 1.0f; }
    else {
        i -= nA;
        if (i >= nB) return;
        in = inB; out = outB; s = sB;
    }
    const int p = i << 2;             // byte index in swizzled output
    const int blk = p >> 10;          // 1024B block
    const int pos = p & 1023;
    const int rb = blk >> 4;          // KB = 1024/64 = 16 k-blocks per row-block
    const int kb = blk & 15;
    const int q = pos >> 4;           // chunk 0..63
    const int quad = q >> 4, l16 = q & 15;
    const int o = pos & 15;           // 0,4,8,12
    const int kh = o >> 3, b0 = o & 7;
    const int r = rb * 16 + l16;
    const int k = kb * 64 + kh * 32 + quad * 8 + b0;
    float4 v = *(const float4*)(in + (size_t)r * 1024 + k);
    v.x *= s; v.y *= s; v.z *= s; v.w *= s;
    out[i] = pack_fp8x4(v);
}

// ---------------- fp32 -> bf16 conversion, two arrays per launch ------------
__global__ __launch_bounds__(256) void cvt2_bf16(
    const float4* __restrict__ inA, ushort4* __restrict__ outA, int nA4,
    const float4* __restrict__ inB, ushort4* __restrict__ outB, int nB4)
{
    int i = blockIdx.x * 256 + threadIdx.x;
    const float4* in;
    ushort4* out;
    if (i < nA4) { in = inA + i; out = outA + i; }
    else {
        i -= nA4;
        if (i >= nB4) return;
        in = inB + i; out = outB + i;
    }
    float4 v = *in;
    ushort4 o;
    o.x = f2bf(v.x); o.y = f2bf(v.y); o.z = f2bf(v.z); o.w = f2bf(v.w);
    *out = o;
}

__global__ __launch_bounds__(256) void cvt_bf16(
    const float4* __restrict__ in, ushort4* __restrict__ out, int n4)
{
    int i = blockIdx.x * 256 + threadIdx.x;
    if (i < n4) {
        float4 v = in[i];
        ushort4 o;
        o.x = f2bf(v.x); o.y = f2bf(v.y); o.z = f2bf(v.z); o.w = f2bf(v.w);
        out[i] = o;
    }
}

// ---------------- fp8 MFMA GEMM on swizzled inputs --------------------------
// C = bf16(fast_tanh(outScale * (A @ B^T))), A:(M,1024) B:(N,1024) e4m3
// pre-swizzled (cvt2_fp8_sw). 128x128 tile, BK=64 bytes, 16 iters. m-fast grid.
__global__ __launch_bounds__(256) void gemm_fp8_bt(
    const unsigned char* __restrict__ A, const unsigned char* __restrict__ B,
    unsigned short* __restrict__ C, int M, int N, float outScale)
{
    __shared__ __align__(16) unsigned char As[8192];   // 8 subtiles x 1024B
    __shared__ __align__(16) unsigned char Bs[8192];
    const int tid = threadIdx.x;
    const int m0 = blockIdx.x * 128;
    const int n0 = blockIdx.y * 128;
    const int wid = tid >> 6;
    const int lane = tid & 63;
    const int quad = lane >> 4;
    const int l16 = lane & 15;
    const int wm = (wid >> 1) * 64;
    const int wn = (wid & 1) * 64;
    const int stA = wm >> 4;          // 0 or 4
    const int stB = wn >> 4;          // 0 or 4
    const int st = tid >> 6;          // staging subtile 0..3
    const int cl = (tid & 63) * 16;   // staging chunk byte

    f32x4 acc[4][4] = {};

    const unsigned char* Ab = A + ((size_t)(m0 >> 4) * 16) * 1024;  // KB=16
    const unsigned char* Bb = B + ((size_t)(n0 >> 4) * 16) * 1024;

    for (int kb = 0; kb < 16; kb++) {
        async16(&As[tid * 16],        Ab + ((size_t)st * 16 + kb) * 1024 + cl);
        async16(&As[4096 + tid * 16], Ab + ((size_t)(st + 4) * 16 + kb) * 1024 + cl);
        async16(&Bs[tid * 16],        Bb + ((size_t)st * 16 + kb) * 1024 + cl);
        async16(&Bs[4096 + tid * 16], Bb + ((size_t)(st + 4) * 16 + kb) * 1024 + cl);
        __syncthreads();

        lx2 a8[4], b8[4];
#pragma unroll
        for (int mt = 0; mt < 4; mt++)
            a8[mt] = *(const lx2*)&As[(stA + mt) * 1024 + lane * 16];
#pragma unroll
        for (int nt = 0; nt < 4; nt++)
            b8[nt] = *(const lx2*)&Bs[(stB + nt) * 1024 + lane * 16];
#pragma unroll
        for (int mt = 0; mt < 4; mt++)
#pragma unroll
            for (int nt = 0; nt < 4; nt++) {
                acc[mt][nt] = __builtin_amdgcn_mfma_f32_16x16x32_fp8_fp8(
                    a8[mt].x, b8[nt].x, acc[mt][nt], 0, 0, 0);
                acc[mt][nt] = __builtin_amdgcn_mfma_f32_16x16x32_fp8_fp8(
                    a8[mt].y, b8[nt].y, acc[mt][nt], 0, 0, 0);
            }
        __syncthreads();
    }

#pragma unroll
    for (int mt = 0; mt < 4; mt++)
#pragma unroll
        for (int nt = 0; nt < 4; nt++)
#pragma unroll
            for (int r = 0; r < 4; r++) {
                const int row = m0 + wm + mt * 16 + quad * 4 + r;
                const int col = n0 + wn + nt * 16 + l16;
                C[(size_t)row * N + col] = f2bf(fast_tanh(acc[mt][nt][r] * outScale));
            }
}

// ---------------- bf16 MFMA GEMM (qproj): C = A @ B^T, bf16 out -------------
__global__ __launch_bounds__(256) void gemm_bf16_bt(
    const unsigned short* __restrict__ A, const unsigned short* __restrict__ B,
    unsigned short* __restrict__ C, int M, int N, int K)
{
    __shared__ unsigned short As[128 * 32];   // 8 KB
    __shared__ unsigned short Bs[128 * 32];   // 8 KB
    const int tid = threadIdx.x;
    const int m0 = blockIdx.x * 128;
    const int n0 = blockIdx.y * 128;
    const int wid = tid >> 6;
    const int lane = tid & 63;
    const int quad = lane >> 4;
    const int l16 = lane & 15;
    const int wm = (wid >> 1) * 64;
    const int wn = (wid & 1) * 64;

    f32x4 acc[4][4] = {};

    const int r0 = tid >> 2;
    const int cc0 = (tid & 3) * 8;

    for (int k0 = 0; k0 < K; k0 += 32) {
        async16(&As[tid * 8],        A + (size_t)(m0 + r0) * K + k0 + cc0);
        async16(&As[2048 + tid * 8], A + (size_t)(m0 + 64 + r0) * K + k0 + cc0);
        async16(&Bs[tid * 8],        B + (size_t)(n0 + r0) * K + k0 + cc0);
        async16(&Bs[2048 + tid * 8], B + (size_t)(n0 + 64 + r0) * K + k0 + cc0);
        __syncthreads();

        bf16x8 af[4], bfr[4];
#pragma unroll
        for (int mt = 0; mt < 4; mt++)
            af[mt] = *(const bf16x8*)&As[(wm + mt * 16 + l16) * 32 + quad * 8];
#pragma unroll
        for (int nt = 0; nt < 4; nt++)
            bfr[nt] = *(const bf16x8*)&Bs[(wn + nt * 16 + l16) * 32 + quad * 8];
#pragma unroll
        for (int mt = 0; mt < 4; mt++)
#pragma unroll
            for (int nt = 0; nt < 4; nt++)
                acc[mt][nt] = __builtin_amdgcn_mfma_f32_16x16x32_bf16(
                    af[mt], bfr[nt], acc[mt][nt], 0, 0, 0);
        __syncthreads();
    }

#pragma unroll
    for (int mt = 0; mt < 4; mt++)
#pragma unroll
        for (int nt = 0; nt < 4; nt++)
#pragma unroll
            for (int r = 0; r < 4; r++) {
                const int row = m0 + wm + mt * 16 + quad * 4 + r;
                const int col = n0 + wn + nt * 16 + l16;
                C[(size_t)row * N + col] = f2bf(acc[mt][nt][r]);
            }
}

// ---------------- wql = ql @ WV^T (32 x 1024, K=1024), fp32, split-K -------
__global__ __launch_bounds__(256) void wql_kernel(
    const float* __restrict__ ql, const float* __restrict__ WV, float* __restrict__ wql)
{
    __shared__ float4 qls[32][32];      // [c][kq]   16 KB
    __shared__ float4 WVs[64][33];      // [n][kq]+pad 33.8 KB
    const int tid = threadIdx.x;
    const int n0 = blockIdx.x * 64;
    const int k0 = blockIdx.y * 128;

    for (int i = tid; i < 1024; i += 256)
        qls[i >> 5][i & 31] = *(const float4*)(ql + (size_t)(i >> 5) * D_MODEL + k0 + (i & 31) * 4);
    for (int i = tid; i < 2048; i += 256)
        WVs[i >> 5][i & 31] = *(const float4*)(WV + (size_t)(n0 + (i >> 5)) * D_MODEL + k0 + (i & 31) * 4);
    __syncthreads();

    const int n = tid & 63;
    const int c0 = (tid >> 6) * 8;
    float acc[8] = {};
    for (int kq = 0; kq < 32; kq++) {
        const float4 wv = WVs[n][kq];
#pragma unroll
        for (int c = 0; c < 8; c++) acc[c] += dot4(qls[c0 + c][kq], wv);
    }
#pragma unroll
    for (int c = 0; c < 8; c++)
        atomicAdd(&wql[(size_t)(c0 + c) * D_MODEL + n0 + n], acc[c]);
}

// ---------------- KV via MFMA ------------------------------------------------
// kv[((b*16+z)*32 + c)*512 + t] = sum_h tanh(H[b,t,z*64+h]) * wql[c,z*64+h]
__global__ __launch_bounds__(256) void kv_gemm(
    const float* __restrict__ H, const unsigned short* __restrict__ wql16,
    float* __restrict__ kv)
{
    __shared__ unsigned short Ks[128 * 64];  // 16 KB   [tl][h] bf16
    __shared__ float kvt[128 * 33];          // 16.9 KB [tl][c] padded
    const int chunk = blockIdx.x;
    const int z = blockIdx.y;
    const int b = chunk >> 2;
    const int t0 = (chunk & 3) * 128;
    const int tid = threadIdx.x;
    const int wid = tid >> 6;
    const int lane = tid & 63;
    const int quad = lane >> 4;
    const int l16 = lane & 15;

#pragma unroll
    for (int it = 0; it < 8; it++) {
        const int idx = it * 256 + tid;
        const int row = idx >> 4;
        const int c4 = (idx & 15) * 4;
        float4 v = *(const float4*)(H + ((size_t)b * T_LEN + t0 + row) * D_MODEL + z * D_K + c4);
        v = fast_tanh4(v);
        ushort4 o;
        o.x = f2bf(v.x); o.y = f2bf(v.y); o.z = f2bf(v.z); o.w = f2bf(v.w);
        *(ushort4*)&Ks[row * 64 + c4] = o;
    }
    bf16x8 bfr[2][2];
#pragma unroll
    for (int ct = 0; ct < 2; ct++)
#pragma unroll
        for (int kh = 0; kh < 2; kh++)
            bfr[ct][kh] = *(const bf16x8*)(wql16 +
                (size_t)(ct * 16 + l16) * D_MODEL + z * D_K + kh * 32 + quad * 8);
    __syncthreads();

    const int wt = wid * 32;
    f32x4 acc[2][2] = {};
#pragma unroll
    for (int tt = 0; tt < 2; tt++) {
        const bf16x8 a0 = *(const bf16x8*)&Ks[(wt + tt * 16 + l16) * 64 + quad * 8];
        const bf16x8 a1 = *(const bf16x8*)&Ks[(wt + tt * 16 + l16) * 64 + 32 + quad * 8];
#pragma unroll
        for (int ct = 0; ct < 2; ct++) {
            acc[tt][ct] = __builtin_amdgcn_mfma_f32_16x16x32_bf16(a0, bfr[ct][0], acc[tt][ct], 0, 0, 0);
            acc[tt][ct] = __builtin_amdgcn_mfma_f32_16x16x32_bf16(a1, bfr[ct][1], acc[tt][ct], 0, 0, 0);
        }
    }
#pragma unroll
    for (int tt = 0; tt < 2; tt++)
#pragma unroll
        for (int ct = 0; ct < 2; ct++)
#pragma unroll
            for (int r = 0; r < 4; r++)
                kvt[(wt + tt * 16 + quad * 4 + r) * 33 + ct * 16 + l16] = acc[tt][ct][r];
    __syncthreads();

    float* outb = kv + (((size_t)b * 16 + z) * 32) * 512 + t0;
#pragma unroll
    for (int it = 0; it < 4; it++) {
        const int idx = it * 256 + tid;
        const int c = idx >> 5;
        const int tq = (idx & 31) * 4;
        float4 v = make_float4(kvt[(tq + 0) * 33 + c], kvt[(tq + 1) * 33 + c],
                               kvt[(tq + 2) * 33 + c], kvt[(tq + 3) * 33 + c]);
        *(float4*)(outb + (size_t)c * 512 + tq) = v;
    }
}

// ---------------- Attention via MFMA: block per (b,z), 8 waves x 4 c-tiles ---
// 512 threads, 64 KB LDS, 2 blocks/CU (4 waves/SIMD). Round-2-verified base +
// (1) kv scalar loads software-pipelined (prefetch nt+1 into rotating regs),
// (2) MFMA cluster under s_setprio(1) (T5: attn-positive, m191),
// (3) race-free partial write per (b,c,z) -> no atomics, no d_out memset.
// Prefetch at nt=31 overreads <=256B past the kv slice -- lands in allocated
// workspace (WKf8 region at worst), loaded-but-unused.
// wkts XOR-swizzled (chunk ^= row&7) via pre-swizzled GLOBAL source (LDS dest
// of global_load_lds must stay lane-linear); matching XOR on ds_read_b128
// address => 0 bank conflicts (verified round 1).
__global__ __launch_bounds__(512, 4) void attn_mfma(
    const unsigned short* __restrict__ qproj, const unsigned short* __restrict__ wkt,
    const float* __restrict__ kv, float* __restrict__ part)
{
    __shared__ unsigned short wkts[512 * 64];   // 64 KB, [t][k] swizzled
    const int z = blockIdx.x;
    const int b = blockIdx.y;
    const int tid = threadIdx.x;
    const int wid = tid >> 6;                   // 0..7
    const int lane = tid & 63;
    const int quad = lane >> 4;
    const int l16 = lane & 15;

    const unsigned short* wb = wkt + (size_t)(b * T_LEN) * D_MODEL + z * D_K;
#pragma unroll
    for (int it = 0; it < 8; it++) {
        const int chunk = it * 512 + tid;
        const int row = chunk >> 3;     // t (0..511)
        const int c = chunk & 7;        // 16B chunk within 128B row
        // inverse-swizzled source: LDS(row,c) holds global chunk (c ^ (row&7))
        async16(&wkts[chunk * 8], wb + (size_t)row * D_MODEL + ((c ^ (row & 7)) * 8));
    }

    bf16x8 af[4][2];
#pragma unroll
    for (int ct = 0; ct < 4; ct++)
#pragma unroll
        for (int kh = 0; kh < 2; kh++)
            af[ct][kh] = *(const bf16x8*)(qproj +
                (size_t)((wid * 4 + ct) * 16 + l16) * D_MODEL + z * D_K + kh * 32 + quad * 8);
    __syncthreads();

    float den[4][4], num[4][4];
#pragma unroll
    for (int ct = 0; ct < 4; ct++)
#pragma unroll
        for (int r = 0; r < 4; r++) { den[ct][r] = 0.f; num[ct][r] = 0.f; }

    // per-lane kv base: kv[((b*16+z)*32 + wid*4 + ct)*512 + nt*16 + l16]
    const float* kvp = kv + (((size_t)b * 16 + z) * 32 + wid * 4) * 512 + l16;
    float kc[4];
#pragma unroll
    for (int ct = 0; ct < 4; ct++) kc[ct] = kvp[ct * 512];

    const int x0 = (quad ^ (l16 & 7)) * 8;        // swizzled read: chunks 0..3
    const int x1 = ((quad ^ 4) ^ (l16 & 7)) * 8;  // swizzled read: chunks 4..7
    for (int nt = 0; nt < 32; nt++) {
        float kn[4];
#pragma unroll
        for (int ct = 0; ct < 4; ct++) kn[ct] = kvp[ct * 512 + (nt + 1) * 16];
        const int rbase = (nt * 16 + l16) * 64;
        const bf16x8 b0 = *(const bf16x8*)&wkts[rbase + x0];
        const bf16x8 b1 = *(const bf16x8*)&wkts[rbase + x1];
        f32x4 a4[4];
        __builtin_amdgcn_s_setprio(1);
#pragma unroll
        for (int ct = 0; ct < 4; ct++) {
            f32x4 a = {};
            a = __builtin_amdgcn_mfma_f32_16x16x32_bf16(af[ct][0], b0, a, 0, 0, 0);
            a = __builtin_amdgcn_mfma_f32_16x16x32_bf16(af[ct][1], b1, a, 0, 0, 0);
            a4[ct] = a;
        }
        __builtin_amdgcn_s_setprio(0);
#pragma unroll
        for (int ct = 0; ct < 4; ct++)
#pragma unroll
            for (int r = 0; r < 4; r++) {
                const float e = __expf(a4[ct][r]);
                den[ct][r] += e;
                num[ct][r] += e * kc[ct];
            }
#pragma unroll
        for (int ct = 0; ct < 4; ct++) kc[ct] = kn[ct];
    }

#pragma unroll
    for (int ct = 0; ct < 4; ct++) {
        float s = 0.f;
#pragma unroll
        for (int r = 0; r < 4; r++) {
            float d = den[ct][r], n = num[ct][r];
#pragma unroll
            for (int off = 1; off < 16; off <<= 1) {
                d += __shfl_xor(d, off, 64);
                n += __shfl_xor(n, off, 64);
            }
            s += n / d;
        }
        s += __shfl_xor(s, 16, 64);
        s += __shfl_xor(s, 32, 64);
        if (lane == 0)
            part[((size_t)(b * N_CLASSES) + wid * 4 + ct) * 16 + z] = s;
    }
}

// ---------------- combine z + apply 1/16 s-mean: out[b,c] -------------------
__global__ __launch_bounds__(256) void attn_reduce(
    const float* __restrict__ part, float* __restrict__ out)
{
    const int i = blockIdx.x * 256 + threadIdx.x;   // bc in [0,1024)
    const float* p = part + (size_t)i * 16;
    float s = 0.f;
#pragma unroll
    for (int zz = 0; zz < 16; zz++) s += p[zz];
    out[i] = s * (1.0f / 16.0f);
}

extern "C" void kernel_launch(void* const* d_in, const int* in_sizes, int n_in,
                              void* d_out, int out_size, void* d_ws, size_t ws_size,
                              hipStream_t stream)
{
    const float* Q  = (const float*)d_in[0];   // (32,16,1024)
    const float* H  = (const float*)d_in[1];   // (32,512,1024)
    const float* ql = (const float*)d_in[2];   // (32,1024)
    const float* WQ = (const float*)d_in[3];   // (1024,1024)
    const float* WK = (const float*)d_in[4];
    const float* WV = (const float*)d_in[5];
    float* out = (float*)d_out;                // (32,32)

    char* ws = (char*)d_ws;
    // Flat layout (no overlays, peak ~101 MB):
    //   0        : Hf8      (16.78 MB)
    //   24MB     : Qb       (1 MB)
    //   25MB     : WQb      (2 MB)
    //   27MB     : qproj_b  (1 MB)
    //   28MB     : wqlb16   (64 KB)
    //   29MB     : part     (64 KB)
    //   30MB     : wqlb f32 (128 KB)
    //   32MB     : wkt_b    (33.5 MB)
    //   64MB     : kv       (33.5 MB)
    //   96MB     : WKf8     (1 MB)
    unsigned char*  Hf8     = (unsigned char*)(ws);
    unsigned short* Qb      = (unsigned short*)(ws + (size_t)25165824);
    unsigned short* WQb     = (unsigned short*)(ws + (size_t)26214400);
    unsigned short* qproj_b = (unsigned short*)(ws + (size_t)28311552);
    unsigned short* wqlb16  = (unsigned short*)(ws + (size_t)29360128);
    float*          part    = (float*)(ws + (size_t)30408704);
    float*          wqlb    = (float*)(ws + (size_t)31457280);
    unsigned short* wkt_b   = (unsigned short*)(ws + (size_t)33554432);
    float*          kv      = (float*)(ws + (size_t)67108864);
    unsigned char*  WKf8    = (unsigned char*)(ws + (size_t)100663296);

    dim3 thr(256);
    // wqlb zero for split-K atomics (own region, no ordering hazard)
    hipMemsetAsync(wqlb, 0, (size_t)N_CLASSES * D_MODEL * sizeof(float), stream);
    // fp8 swizzled conversions: H (scale 1), WK (x512: N(0,1e-3) subnormal in e4m3)
    cvt2_fp8_sw<<<dim3(17408), thr, 0, stream>>>(
        H, (int*)Hf8, 4194304,
        WK, (int*)WKf8, 262144, 512.0f);
    // wkt = fast_tanh((H8 @ WK8^T)/512)  (16384 x 1024), bf16 out. m-fast grid.
    gemm_fp8_bt<<<dim3(128, 8), thr, 0, stream>>>(Hf8, WKf8, wkt_b, 16384, 1024, 1.0f / 512.0f);
    // bf16 conversions: Q, WQ
    cvt2_bf16<<<dim3(1536), thr, 0, stream>>>(
        (const float4*)Q, (ushort4*)Qb, 131072,
        (const float4*)WQ, (ushort4*)WQb, 262144);
    // qproj = Q @ WQ^T  (512 x 1024), bf16
    gemm_bf16_bt<<<dim3(4, 8), thr, 0, stream>>>(Qb, WQb, qproj_b, 512, 1024, 1024);
    // Wql = ql @ WV^T  (32 x 1024), fp32 split-K
    wql_kernel<<<dim3(16, 8), thr, 0, stream>>>(ql, WV, wqlb);
    // wql -> bf16 for the kv MFMA
    cvt_bf16<<<dim3(32), thr, 0, stream>>>((const float4*)wqlb, (ushort4*)wqlb16, 8192);
    // kv(b,z,c,t) via MFMA
    kv_gemm<<<dim3(128, 16), thr, 0, stream>>>(H, wqlb16, kv);
    // fused scores -> exp -> num/den partials per (b,c,z)
    attn_mfma<<<dim3(16, 32), dim3(512), 0, stream>>>(qproj_b, wkt_b, kv, part);
    // combine z + 1/16 s-mean
    attn_reduce<<<dim3(4), thr, 0, stream>>>(part, out);
}

// Round 5
// 206.953 us; speedup vs baseline: 1.5145x; 1.1617x over previous
//
#include <hip/hip_runtime.h>
#include <hip/hip_bf16.h>
#include <math.h>

#define D_MODEL 1024
#define N_HEADS 16
#define D_K 64
#define N_CLASSES 32
#define S_LEN 16
#define BATCH 32
#define T_LEN 512

typedef __bf16 bf16_t;
typedef bf16_t bf16x8 __attribute__((ext_vector_type(8)));
typedef float f32x4 __attribute__((ext_vector_type(4)));
typedef long lx2 __attribute__((ext_vector_type(2)));

__device__ inline unsigned short f2bf(float f) {
    unsigned int u = __float_as_uint(f);
    unsigned int r = (u + 0x7FFFu + ((u >> 16) & 1u)) >> 16;   // RNE
    return (unsigned short)r;
}
// fast tanh: (e-1)/(e+1), e = exp(2x). Valid for |x| < 40. rel err ~1e-6.
__device__ inline float fast_tanh(float x) {
    float e = __expf(2.0f * x);
    return (e - 1.0f) * __builtin_amdgcn_rcpf(e + 1.0f);
}
__device__ inline float4 fast_tanh4(float4 v) {
    return make_float4(fast_tanh(v.x), fast_tanh(v.y), fast_tanh(v.z), fast_tanh(v.w));
}
__device__ inline float dot4(float4 a, float4 b) {
    return a.x * b.x + a.y * b.y + a.z * b.z + a.w * b.w;
}
// bare v_exp_f32: D = 2^x (we pre-scale scores by log2e via Q)
__device__ inline float exp2_fast(float x) {
    float r;
    asm("v_exp_f32 %0, %1" : "=v"(r) : "v"(x));
    return r;
}
// pack 4 floats -> 4 e4m3 bytes (OCP, HW cvt)
__device__ inline int pack_fp8x4(float4 v) {
    int p = __builtin_amdgcn_cvt_pk_fp8_f32(v.x, v.y, 0, false);
    p = __builtin_amdgcn_cvt_pk_fp8_f32(v.z, v.w, p, true);
    return p;
}
// 8 consecutive f32 -> bf16x8 fragment
__device__ inline bf16x8 bf8_from_f32(const float* p) {
    float4 a = *(const float4*)p;
    float4 b = *(const float4*)(p + 4);
    union { bf16x8 v; unsigned short s[8]; } u;
    u.s[0] = f2bf(a.x); u.s[1] = f2bf(a.y); u.s[2] = f2bf(a.z); u.s[3] = f2bf(a.w);
    u.s[4] = f2bf(b.x); u.s[5] = f2bf(b.y); u.s[6] = f2bf(b.z); u.s[7] = f2bf(b.w);
    return u.v;
}

// async global->LDS, 16 bytes per lane (global_load_lds_dwordx4)
__device__ inline void async16(void* lds, const void* g) {
    __builtin_amdgcn_global_load_lds(
        (const __attribute__((address_space(1))) unsigned int*)g,
        (__attribute__((address_space(3))) unsigned int*)lds, 16, 0, 0);
}

// ================= prep: wql-splitK ∥ fp8-swizzle cvt ∥ bf16 cvt ============
// Roles by blockIdx range; wql blocks FIRST (256 latency-light blocks hide
// under the 17408-block streaming cvt). Round-3 lesson: the merge mechanics
// are fine; the failure was an uncoalesced wql rewrite. Here wql keeps the
// PROVEN split-K LDS structure (coalesced float4 loads + atomics), shrunk to
// 64-float k-chunks so union LDS = 25.6 KB (6 blocks/CU for the cvt roles).
// fp8 swizzled layout (unchanged): for each 16-row x 64-byte subtile (rb,kb),
// a 1024B block at ((rb*16+kb)*1024); byte (quad*16+l16)*16 + kh*8 + b0 holds
// src[rb*16+l16][kb*64+kh*32+quad*8+b0].
// Q is scaled by log2(e) at cvt: scores then feed bare v_exp_f32 (exp2) in
// attn; num/den ratio is invariant to the uniform scale.
__global__ __launch_bounds__(256) void prep_kernel(
    const float* __restrict__ H, int* __restrict__ Hf8,
    const float* __restrict__ WK, int* __restrict__ WKf8,
    const float4* __restrict__ Q, ushort4* __restrict__ Qb,
    const float4* __restrict__ WQ, ushort4* __restrict__ WQb,
    const float* __restrict__ ql, const float* __restrict__ WV,
    float* __restrict__ wql)
{
    __shared__ __align__(16) char psm[25600];
    const int bid = blockIdx.x;
    const int tid = threadIdx.x;
    if (bid < 256) {
        // ---- wql split-K: wql[c][n] += sum_{k0..k0+63} ql[c][k]*WV[n][k] ----
        float4 (*qls)[16] = (float4(*)[16])psm;               // [32][16]  8 KB
        float4 (*WVs)[17] = (float4(*)[17])(psm + 8192);      // [64][17] 17.4 KB
        const int n0 = (bid & 15) * 64;
        const int k0 = (bid >> 4) * 64;
        for (int i = tid; i < 512; i += 256)
            qls[i >> 4][i & 15] = *(const float4*)(ql + (size_t)(i >> 4) * D_MODEL + k0 + (i & 15) * 4);
        for (int i = tid; i < 1024; i += 256)
            WVs[i >> 4][i & 15] = *(const float4*)(WV + (size_t)(n0 + (i >> 4)) * D_MODEL + k0 + (i & 15) * 4);
        __syncthreads();

        const int n = tid & 63;
        const int c0 = (tid >> 6) * 8;
        float acc[8] = {};
        for (int kq = 0; kq < 16; kq++) {
            const float4 wv = WVs[n][kq];
#pragma unroll
            for (int c = 0; c < 8; c++) acc[c] += dot4(qls[c0 + c][kq], wv);
        }
#pragma unroll
        for (int c = 0; c < 8; c++)
            atomicAdd(&wql[(size_t)(c0 + c) * D_MODEL + n0 + n], acc[c]);
    } else if (bid < 17664) {
        // ---- fp8 swizzled cvt: H (4194304 words, s=1), WK (262144, x512) ----
        int i = (bid - 256) * 256 + tid;
        const float* in; int* out; float s;
        if (i < 4194304) { in = H; out = Hf8; s = 1.0f; }
        else { i -= 4194304; in = WK; out = WKf8; s = 512.0f; }
        const int p = i << 2;
        const int blk = p >> 10;
        const int pos = p & 1023;
        const int rb = blk >> 4, kb = blk & 15;
        const int q = pos >> 4;
        const int quad = q >> 4, l16 = q & 15;
        const int o = pos & 15;
        const int kh = o >> 3, b0 = o & 7;
        const int r = rb * 16 + l16;
        const int k = kb * 64 + kh * 32 + quad * 8 + b0;
        float4 v = *(const float4*)(in + (size_t)r * 1024 + k);
        v.x *= s; v.y *= s; v.z *= s; v.w *= s;
        out[i] = pack_fp8x4(v);
    } else {
        // ---- bf16 cvt: Q (131072 float4, x log2e), WQ (262144 float4) ------
        int i = (bid - 17664) * 256 + tid;
        const float4* in; ushort4* out; float s;
        if (i < 131072) { in = Q + i; out = Qb + i; s = 1.4426950408889634f; }
        else { i -= 131072; in = WQ + i; out = WQb + i; s = 1.0f; }
        float4 v = *in;
        ushort4 o;
        o.x = f2bf(v.x * s); o.y = f2bf(v.y * s); o.z = f2bf(v.z * s); o.w = f2bf(v.w * s);
        *out = o;
    }
}

// ================= gemms: fp8 GEMM ∥ qproj bf16 GEMM ∥ kv GEMM ==============
// Round-3-verified merge (correctness-passed there; R3 arithmetic says this
// merge + attn partials saved ~18 us while the wql rewrite cost 91).
// kv role reads wqlb f32 directly (in-register cvt) -> cvt_bf16 launch gone.
__global__ __launch_bounds__(256) void gemms_kernel(
    const unsigned char* __restrict__ A8, const unsigned char* __restrict__ B8,
    unsigned short* __restrict__ wkt_b,
    const unsigned short* __restrict__ Qb, const unsigned short* __restrict__ WQb,
    unsigned short* __restrict__ qproj_b,
    const float* __restrict__ H, const float* __restrict__ wql,
    float* __restrict__ kv)
{
    __shared__ __align__(16) char smem[33280];
    const int bid = blockIdx.x;
    const int tid = threadIdx.x;
    const int wid = tid >> 6;
    const int lane = tid & 63;
    const int quad = lane >> 4;
    const int l16 = lane & 15;

    if (bid < 1024) {
        // ---- fp8 GEMM: wkt = bf16(fast_tanh((H8 @ WK8^T)/512)), 16384x1024 ---
        unsigned char* As = (unsigned char*)smem;          // 8 KB
        unsigned char* Bs = (unsigned char*)smem + 8192;   // 8 KB
        const int m0 = (bid & 127) * 128;   // m-fast grid
        const int n0 = (bid >> 7) * 128;
        const int wm = (wid >> 1) * 64;
        const int wn = (wid & 1) * 64;
        const int stA = wm >> 4;
        const int stB = wn >> 4;
        const int st = wid;
        const int cl = lane * 16;

        f32x4 acc[4][4] = {};
        const unsigned char* Ab = A8 + ((size_t)(m0 >> 4) * 16) * 1024;
        const unsigned char* Bb = B8 + ((size_t)(n0 >> 4) * 16) * 1024;

        for (int kb = 0; kb < 16; kb++) {
            async16(&As[tid * 16],        Ab + ((size_t)st * 16 + kb) * 1024 + cl);
            async16(&As[4096 + tid * 16], Ab + ((size_t)(st + 4) * 16 + kb) * 1024 + cl);
            async16(&Bs[tid * 16],        Bb + ((size_t)st * 16 + kb) * 1024 + cl);
            async16(&Bs[4096 + tid * 16], Bb + ((size_t)(st + 4) * 16 + kb) * 1024 + cl);
            __syncthreads();

            lx2 a8[4], b8[4];
#pragma unroll
            for (int mt = 0; mt < 4; mt++)
                a8[mt] = *(const lx2*)&As[(stA + mt) * 1024 + lane * 16];
#pragma unroll
            for (int nt = 0; nt < 4; nt++)
                b8[nt] = *(const lx2*)&Bs[(stB + nt) * 1024 + lane * 16];
#pragma unroll
            for (int mt = 0; mt < 4; mt++)
#pragma unroll
                for (int nt = 0; nt < 4; nt++) {
                    acc[mt][nt] = __builtin_amdgcn_mfma_f32_16x16x32_fp8_fp8(
                        a8[mt].x, b8[nt].x, acc[mt][nt], 0, 0, 0);
                    acc[mt][nt] = __builtin_amdgcn_mfma_f32_16x16x32_fp8_fp8(
                        a8[mt].y, b8[nt].y, acc[mt][nt], 0, 0, 0);
                }
            __syncthreads();
        }

#pragma unroll
        for (int mt = 0; mt < 4; mt++)
#pragma unroll
            for (int nt = 0; nt < 4; nt++)
#pragma unroll
                for (int r = 0; r < 4; r++) {
                    const int row = m0 + wm + mt * 16 + quad * 4 + r;
                    const int col = n0 + wn + nt * 16 + l16;
                    wkt_b[(size_t)row * 1024 + col] =
                        f2bf(fast_tanh(acc[mt][nt][r] * (1.0f / 512.0f)));
                }
    } else if (bid < 1056) {
        // ---- qproj bf16 GEMM: qproj = Qb @ WQb^T (512 x 1024, K=1024) -------
        unsigned short* As = (unsigned short*)smem;            // 8 KB
        unsigned short* Bs = (unsigned short*)(smem + 8192);   // 8 KB
        const int q = bid - 1024;
        const int m0 = (q & 3) * 128;
        const int n0 = (q >> 2) * 128;
        const int wm = (wid >> 1) * 64;
        const int wn = (wid & 1) * 64;

        f32x4 acc[4][4] = {};
        const int r0 = tid >> 2;
        const int cc0 = (tid & 3) * 8;

        for (int k0 = 0; k0 < 1024; k0 += 32) {
            async16(&As[tid * 8],        Qb  + (size_t)(m0 + r0) * 1024 + k0 + cc0);
            async16(&As[2048 + tid * 8], Qb  + (size_t)(m0 + 64 + r0) * 1024 + k0 + cc0);
            async16(&Bs[tid * 8],        WQb + (size_t)(n0 + r0) * 1024 + k0 + cc0);
            async16(&Bs[2048 + tid * 8], WQb + (size_t)(n0 + 64 + r0) * 1024 + k0 + cc0);
            __syncthreads();

            bf16x8 af[4], bfr[4];
#pragma unroll
            for (int mt = 0; mt < 4; mt++)
                af[mt] = *(const bf16x8*)&As[(wm + mt * 16 + l16) * 32 + quad * 8];
#pragma unroll
            for (int nt = 0; nt < 4; nt++)
                bfr[nt] = *(const bf16x8*)&Bs[(wn + nt * 16 + l16) * 32 + quad * 8];
#pragma unroll
            for (int mt = 0; mt < 4; mt++)
#pragma unroll
                for (int nt = 0; nt < 4; nt++)
                    acc[mt][nt] = __builtin_amdgcn_mfma_f32_16x16x32_bf16(
                        af[mt], bfr[nt], acc[mt][nt], 0, 0, 0);
            __syncthreads();
        }

#pragma unroll
        for (int mt = 0; mt < 4; mt++)
#pragma unroll
            for (int nt = 0; nt < 4; nt++)
#pragma unroll
                for (int r = 0; r < 4; r++) {
                    const int row = m0 + wm + mt * 16 + quad * 4 + r;
                    const int col = n0 + wn + nt * 16 + l16;
                    qproj_b[(size_t)row * 1024 + col] = f2bf(acc[mt][nt][r]);
                }
    } else {
        // ---- kv GEMM: kv[((b*16+z)*32+c)*512+t] = sum_h tanh(H)*wql --------
        unsigned short* Ks = (unsigned short*)smem;             // 16 KB [tl][h]
        float* kvt = (float*)(smem + 16384);                    // 16.9 KB [tl][c] pad
        const int q = bid - 1056;
        const int chunk = q & 127;
        const int z = q >> 7;
        const int b = chunk >> 2;
        const int t0 = (chunk & 3) * 128;

#pragma unroll
        for (int it = 0; it < 8; it++) {
            const int idx = it * 256 + tid;
            const int row = idx >> 4;
            const int c4 = (idx & 15) * 4;
            float4 v = *(const float4*)(H + ((size_t)b * T_LEN + t0 + row) * D_MODEL + z * D_K + c4);
            v = fast_tanh4(v);
            ushort4 o;
            o.x = f2bf(v.x); o.y = f2bf(v.y); o.z = f2bf(v.z); o.w = f2bf(v.w);
            *(ushort4*)&Ks[row * 64 + c4] = o;
        }
        bf16x8 bfr[2][2];
#pragma unroll
        for (int ct = 0; ct < 2; ct++)
#pragma unroll
            for (int kh = 0; kh < 2; kh++)
                bfr[ct][kh] = bf8_from_f32(wql +
                    (size_t)(ct * 16 + l16) * D_MODEL + z * D_K + kh * 32 + quad * 8);
        __syncthreads();

        const int wt = wid * 32;
        f32x4 acc[2][2] = {};
#pragma unroll
        for (int tt = 0; tt < 2; tt++) {
            const bf16x8 a0 = *(const bf16x8*)&Ks[(wt + tt * 16 + l16) * 64 + quad * 8];
            const bf16x8 a1 = *(const bf16x8*)&Ks[(wt + tt * 16 + l16) * 64 + 32 + quad * 8];
#pragma unroll
            for (int ct = 0; ct < 2; ct++) {
                acc[tt][ct] = __builtin_amdgcn_mfma_f32_16x16x32_bf16(a0, bfr[ct][0], acc[tt][ct], 0, 0, 0);
                acc[tt][ct] = __builtin_amdgcn_mfma_f32_16x16x32_bf16(a1, bfr[ct][1], acc[tt][ct], 0, 0, 0);
            }
        }
#pragma unroll
        for (int tt = 0; tt < 2; tt++)
#pragma unroll
            for (int ct = 0; ct < 2; ct++)
#pragma unroll
                for (int r = 0; r < 4; r++)
                    kvt[(wt + tt * 16 + quad * 4 + r) * 33 + ct * 16 + l16] = acc[tt][ct][r];
        __syncthreads();

        float* outb = kv + (((size_t)b * 16 + z) * 32) * 512 + t0;
#pragma unroll
        for (int it = 0; it < 4; it++) {
            const int idx = it * 256 + tid;
            const int c = idx >> 5;
            const int tq = (idx & 31) * 4;
            float4 v = make_float4(kvt[(tq + 0) * 33 + c], kvt[(tq + 1) * 33 + c],
                                   kvt[(tq + 2) * 33 + c], kvt[(tq + 3) * 33 + c]);
            *(float4*)(outb + (size_t)c * 512 + tq) = v;
        }
    }
}

// ================= attn: block per (b,z), 8 waves x 4 c-tiles ===============
// 512 threads, 64 KB LDS, 2 blocks/CU (4 waves/SIMD). Round-4-verified base;
// scores are pre-scaled by log2e (via Q) so the exp is ONE v_exp_f32 (exp2)
// instead of mul+exp -- removes 16 v_mul/iter/thread from the hot loop.
// kv prefetch + setprio kept (neutral, zero cost). Race-free partial write
// per (b,c,z) -> no atomics, no d_out memset. Prefetch at nt=31 overreads
// <=256B past the kv slice (lands in allocated ws, unused).
__global__ __launch_bounds__(512, 4) void attn_mfma(
    const unsigned short* __restrict__ qproj, const unsigned short* __restrict__ wkt,
    const float* __restrict__ kv, float* __restrict__ part)
{
    __shared__ unsigned short wkts[512 * 64];   // 64 KB, [t][k] swizzled
    const int z = blockIdx.x;
    const int b = blockIdx.y;
    const int tid = threadIdx.x;
    const int wid = tid >> 6;                   // 0..7
    const int lane = tid & 63;
    const int quad = lane >> 4;
    const int l16 = lane & 15;

    const unsigned short* wb = wkt + (size_t)(b * T_LEN) * D_MODEL + z * D_K;
#pragma unroll
    for (int it = 0; it < 8; it++) {
        const int chunk = it * 512 + tid;
        const int row = chunk >> 3;     // t (0..511)
        const int c = chunk & 7;        // 16B chunk within 128B row
        // inverse-swizzled source: LDS(row,c) holds global chunk (c ^ (row&7))
        async16(&wkts[chunk * 8], wb + (size_t)row * D_MODEL + ((c ^ (row & 7)) * 8));
    }

    bf16x8 af[4][2];
#pragma unroll
    for (int ct = 0; ct < 4; ct++)
#pragma unroll
        for (int kh = 0; kh < 2; kh++)
            af[ct][kh] = *(const bf16x8*)(qproj +
                (size_t)((wid * 4 + ct) * 16 + l16) * D_MODEL + z * D_K + kh * 32 + quad * 8);
    __syncthreads();

    float den[4][4], num[4][4];
#pragma unroll
    for (int ct = 0; ct < 4; ct++)
#pragma unroll
        for (int r = 0; r < 4; r++) { den[ct][r] = 0.f; num[ct][r] = 0.f; }

    // per-lane kv base: kv[((b*16+z)*32 + wid*4 + ct)*512 + nt*16 + l16]
    const float* kvp = kv + (((size_t)b * 16 + z) * 32 + wid * 4) * 512 + l16;
    float kc[4];
#pragma unroll
    for (int ct = 0; ct < 4; ct++) kc[ct] = kvp[ct * 512];

    const int x0 = (quad ^ (l16 & 7)) * 8;        // swizzled read: chunks 0..3
    const int x1 = ((quad ^ 4) ^ (l16 & 7)) * 8;  // swizzled read: chunks 4..7
    for (int nt = 0; nt < 32; nt++) {
        float kn[4];
#pragma unroll
        for (int ct = 0; ct < 4; ct++) kn[ct] = kvp[ct * 512 + (nt + 1) * 16];
        const int rbase = (nt * 16 + l16) * 64;
        const bf16x8 b0 = *(const bf16x8*)&wkts[rbase + x0];
        const bf16x8 b1 = *(const bf16x8*)&wkts[rbase + x1];
        f32x4 a4[4];
        __builtin_amdgcn_s_setprio(1);
#pragma unroll
        for (int ct = 0; ct < 4; ct++) {
            f32x4 a = {};
            a = __builtin_amdgcn_mfma_f32_16x16x32_bf16(af[ct][0], b0, a, 0, 0, 0);
            a = __builtin_amdgcn_mfma_f32_16x16x32_bf16(af[ct][1], b1, a, 0, 0, 0);
            a4[ct] = a;
        }
        __builtin_amdgcn_s_setprio(0);
#pragma unroll
        for (int ct = 0; ct < 4; ct++)
#pragma unroll
            for (int r = 0; r < 4; r++) {
                const float e = exp2_fast(a4[ct][r]);
                den[ct][r] += e;
                num[ct][r] += e * kc[ct];
            }
#pragma unroll
        for (int ct = 0; ct < 4; ct++) kc[ct] = kn[ct];
    }

#pragma unroll
    for (int ct = 0; ct < 4; ct++) {
        float s = 0.f;
#pragma unroll
        for (int r = 0; r < 4; r++) {
            float d = den[ct][r], n = num[ct][r];
#pragma unroll
            for (int off = 1; off < 16; off <<= 1) {
                d += __shfl_xor(d, off, 64);
                n += __shfl_xor(n, off, 64);
            }
            s += n / d;
        }
        s += __shfl_xor(s, 16, 64);
        s += __shfl_xor(s, 32, 64);
        if (lane == 0)
            part[((size_t)(b * N_CLASSES) + wid * 4 + ct) * 16 + z] = s;
    }
}

// ---------------- combine z + apply 1/16 s-mean: out[b,c] -------------------
__global__ __launch_bounds__(256) void attn_reduce(
    const float* __restrict__ part, float* __restrict__ out)
{
    const int i = blockIdx.x * 256 + threadIdx.x;   // bc in [0,1024)
    const float* p = part + (size_t)i * 16;
    float s = 0.f;
#pragma unroll
    for (int zz = 0; zz < 16; zz++) s += p[zz];
    out[i] = s * (1.0f / 16.0f);
}

extern "C" void kernel_launch(void* const* d_in, const int* in_sizes, int n_in,
                              void* d_out, int out_size, void* d_ws, size_t ws_size,
                              hipStream_t stream)
{
    const float* Q  = (const float*)d_in[0];   // (32,16,1024)
    const float* H  = (const float*)d_in[1];   // (32,512,1024)
    const float* ql = (const float*)d_in[2];   // (32,1024)
    const float* WQ = (const float*)d_in[3];   // (1024,1024)
    const float* WK = (const float*)d_in[4];
    const float* WV = (const float*)d_in[5];
    float* out = (float*)d_out;                // (32,32)

    char* ws = (char*)d_ws;
    // Flat layout (no overlays, peak ~101 MB):
    //   0        : Hf8      (16.78 MB)
    //   24MB     : Qb       (1 MB)
    //   25MB     : WQb      (2 MB)
    //   27MB     : qproj_b  (1 MB)
    //   29MB     : part     (64 KB)
    //   30MB     : wqlb f32 (128 KB)
    //   32MB     : wkt_b    (33.5 MB)
    //   64MB     : kv       (33.5 MB)
    //   96MB     : WKf8     (1 MB)
    unsigned char*  Hf8     = (unsigned char*)(ws);
    unsigned short* Qb      = (unsigned short*)(ws + (size_t)25165824);
    unsigned short* WQb     = (unsigned short*)(ws + (size_t)26214400);
    unsigned short* qproj_b = (unsigned short*)(ws + (size_t)28311552);
    float*          part    = (float*)(ws + (size_t)30408704);
    float*          wqlb    = (float*)(ws + (size_t)31457280);
    unsigned short* wkt_b   = (unsigned short*)(ws + (size_t)33554432);
    float*          kv      = (float*)(ws + (size_t)67108864);
    unsigned char*  WKf8    = (unsigned char*)(ws + (size_t)100663296);

    dim3 thr(256);
    // wqlb zero for split-K atomics
    hipMemsetAsync(wqlb, 0, (size_t)N_CLASSES * D_MODEL * sizeof(float), stream);
    // prep: wql (256) + fp8 cvt (17408) + bf16 cvt (1536) = 19200 blocks
    prep_kernel<<<dim3(19200), thr, 0, stream>>>(
        H, (int*)Hf8, WK, (int*)WKf8,
        (const float4*)Q, (ushort4*)Qb,
        (const float4*)WQ, (ushort4*)WQb,
        ql, WV, wqlb);
    // gemms: fp8 wkt GEMM (1024) + qproj (32) + kv (2048) = 3104 blocks
    gemms_kernel<<<dim3(3104), thr, 0, stream>>>(
        Hf8, WKf8, wkt_b, Qb, WQb, qproj_b, H, wqlb, kv);
    // fused scores -> exp2 -> num/den partials per (b,c,z)
    attn_mfma<<<dim3(16, 32), dim3(512), 0, stream>>>(qproj_b, wkt_b, kv, part);
    // combine z + 1/16 s-mean
    attn_reduce<<<dim3(4), thr, 0, stream>>>(part, out);
}

// Round 6
// 201.272 us; speedup vs baseline: 1.5572x; 1.0282x over previous
//
#include <hip/hip_runtime.h>
#include <hip/hip_bf16.h>
#include <math.h>

#define D_MODEL 1024
#define N_HEADS 16
#define D_K 64
#define N_CLASSES 32
#define S_LEN 16
#define BATCH 32
#define T_LEN 512

typedef __bf16 bf16_t;
typedef bf16_t bf16x8 __attribute__((ext_vector_type(8)));
typedef float f32x4 __attribute__((ext_vector_type(4)));
typedef long lx2 __attribute__((ext_vector_type(2)));

__device__ inline unsigned short f2bf(float f) {
    unsigned int u = __float_as_uint(f);
    unsigned int r = (u + 0x7FFFu + ((u >> 16) & 1u)) >> 16;   // RNE
    return (unsigned short)r;
}
// fast tanh: (e-1)/(e+1), e = exp(2x). Valid for |x| < 40. rel err ~1e-6.
__device__ inline float fast_tanh(float x) {
    float e = __expf(2.0f * x);
    return (e - 1.0f) * __builtin_amdgcn_rcpf(e + 1.0f);
}
__device__ inline float4 fast_tanh4(float4 v) {
    return make_float4(fast_tanh(v.x), fast_tanh(v.y), fast_tanh(v.z), fast_tanh(v.w));
}
__device__ inline float dot4(float4 a, float4 b) {
    return a.x * b.x + a.y * b.y + a.z * b.z + a.w * b.w;
}
// bare v_exp_f32: D = 2^x (scores pre-scaled by log2e via Q)
__device__ inline float exp2_fast(float x) {
    float r;
    asm("v_exp_f32 %0, %1" : "=v"(r) : "v"(x));
    return r;
}
// pack 4 floats -> 4 e4m3 bytes (OCP, HW cvt)
__device__ inline int pack_fp8x4(float4 v) {
    int p = __builtin_amdgcn_cvt_pk_fp8_f32(v.x, v.y, 0, false);
    p = __builtin_amdgcn_cvt_pk_fp8_f32(v.z, v.w, p, true);
    return p;
}
// 8 consecutive f32 -> bf16x8 fragment
__device__ inline bf16x8 bf8_from_f32(const float* p) {
    float4 a = *(const float4*)p;
    float4 b = *(const float4*)(p + 4);
    union { bf16x8 v; unsigned short s[8]; } u;
    u.s[0] = f2bf(a.x); u.s[1] = f2bf(a.y); u.s[2] = f2bf(a.z); u.s[3] = f2bf(a.w);
    u.s[4] = f2bf(b.x); u.s[5] = f2bf(b.y); u.s[6] = f2bf(b.z); u.s[7] = f2bf(b.w);
    return u.v;
}

// async global->LDS, 16 bytes per lane (global_load_lds_dwordx4)
__device__ inline void async16(void* lds, const void* g) {
    __builtin_amdgcn_global_load_lds(
        (const __attribute__((address_space(1))) unsigned int*)g,
        (__attribute__((address_space(3))) unsigned int*)lds, 16, 0, 0);
}

// ================= prep: wql-splitK ∥ fp8-swizzle cvt ∥ bf16 cvt ============
// Roles by blockIdx range; wql blocks FIRST (256 latency-light blocks hide
// under the streaming cvt blocks).
// fp8 cvt is LDS-MEDIATED this round: the direct gather read 2x32B segments
// per 4KB-strided row (~2-4x transaction amplification on 67MB of H). Now a
// block stages 16 rows x 1KB CONTIGUOUSLY (256B segments per wave-load) into
// LDS, gathers the swizzle pattern from LDS (cheap, <=4-way conflict with
// [16][260] padding), and writes out[i] coalesced. Output bytes identical to
// the old cvt2_fp8_sw: for each 16-row x 64-byte subtile (rb,kb), a 1024B
// block at ((rb*16+kb)*1024); byte (quad*16+l16)*16 + kh*8 + b0 holds
// src[rb*16+l16][kb*64+kh*32+quad*8+b0].
// Q is scaled by log2(e) at cvt: scores then use bare v_exp_f32 in attn.
__global__ __launch_bounds__(256) void prep_kernel(
    const float* __restrict__ H, int* __restrict__ Hf8,
    const float* __restrict__ WK, int* __restrict__ WKf8,
    const float4* __restrict__ Q, ushort4* __restrict__ Qb,
    const float4* __restrict__ WQ, ushort4* __restrict__ WQb,
    const float* __restrict__ ql, const float* __restrict__ WV,
    float* __restrict__ wql)
{
    __shared__ __align__(16) char psm[25600];
    const int bid = blockIdx.x;
    const int tid = threadIdx.x;
    if (bid < 256) {
        // ---- wql split-K: wql[c][n] += sum_{k0..k0+63} ql[c][k]*WV[n][k] ----
        float4 (*qls)[16] = (float4(*)[16])psm;               // [32][16]  8 KB
        float4 (*WVs)[17] = (float4(*)[17])(psm + 8192);      // [64][17] 17.4 KB
        const int n0 = (bid & 15) * 64;
        const int k0 = (bid >> 4) * 64;
        for (int i = tid; i < 512; i += 256)
            qls[i >> 4][i & 15] = *(const float4*)(ql + (size_t)(i >> 4) * D_MODEL + k0 + (i & 15) * 4);
        for (int i = tid; i < 1024; i += 256)
            WVs[i >> 4][i & 15] = *(const float4*)(WV + (size_t)(n0 + (i >> 4)) * D_MODEL + k0 + (i & 15) * 4);
        __syncthreads();

        const int n = tid & 63;
        const int c0 = (tid >> 6) * 8;
        float acc[8] = {};
        for (int kq = 0; kq < 16; kq++) {
            const float4 wv = WVs[n][kq];
#pragma unroll
            for (int c = 0; c < 8; c++) acc[c] += dot4(qls[c0 + c][kq], wv);
        }
#pragma unroll
        for (int c = 0; c < 8; c++)
            atomicAdd(&wql[(size_t)(c0 + c) * D_MODEL + n0 + n], acc[c]);
    } else if (bid < 4608) {
        // ---- LDS-mediated fp8 swizzle cvt: H (4096 CTAs), WK (256 CTAs) ----
        // CTA j handles 1024 output ints = 4 swizzled 1024B blocks = rows
        // rb*16..+15, cols kb0*64 .. +255 of the source.
        float (*L)[260] = (float(*)[260])psm;   // 16 x 260 floats = 16.6 KB
        int j = bid - 256;
        const float* in; int* out; float s; int jj;
        if (j < 4096) { in = H; out = Hf8; s = 1.0f; jj = j; }
        else { in = WK; out = WKf8; s = 512.0f; jj = j - 4096; }
        const int rb = jj >> 2;
        const int kb0 = (jj & 3) * 4;
        const float* base = in + (size_t)rb * 16 * 1024 + kb0 * 64;
#pragma unroll
        for (int it = 0; it < 4; it++) {
            const int idx = it * 256 + tid;
            const int row = idx >> 6;            // 0..15
            const int c0 = (idx & 63) * 4;       // 0..252
            *(float4*)&L[row][c0] = *(const float4*)(base + (size_t)row * 1024 + c0);
        }
        __syncthreads();
        const int quad = tid >> 6;
        const int l16 = (tid >> 2) & 15;
        const int kh = (tid & 3) >> 1;
        const int b0 = (tid & 1) * 4;
        const int klb = kh * 32 + quad * 8 + b0;
        int* outp = out + (size_t)jj * 1024 + tid;
#pragma unroll
        for (int p = 0; p < 4; p++) {
            float4 v = *(const float4*)&L[l16][p * 64 + klb];
            v.x *= s; v.y *= s; v.z *= s; v.w *= s;
            outp[p * 256] = pack_fp8x4(v);
        }
    } else {
        // ---- bf16 cvt: Q (131072 float4, x log2e), WQ (262144 float4) ------
        int i = (bid - 4608) * 256 + tid;
        const float4* in; ushort4* out; float s;
        if (i < 131072) { in = Q + i; out = Qb + i; s = 1.4426950408889634f; }
        else { i -= 131072; in = WQ + i; out = WQb + i; s = 1.0f; }
        float4 v = *in;
        ushort4 o;
        o.x = f2bf(v.x * s); o.y = f2bf(v.y * s); o.z = f2bf(v.z * s); o.w = f2bf(v.w * s);
        *out = o;
    }
}

// ================= gemms: fp8 GEMM ∥ qproj bf16 GEMM ∥ kv GEMM ==============
// fp8 role upgraded to the T3-minimum double-buffer pipeline: prologue stages
// tile 0; each iter issues the stage of tile kb+1 into the other buffer
// BEFORE ds_read+MFMA of tile kb, with ONE vmcnt(0)+barrier per iter (the
// __syncthreads drain now happens after 32 MFMAs instead of immediately
// after issue -> HBM latency hidden). LDS 2x(8+8)=32KB fits the 33280 union.
__global__ __launch_bounds__(256) void gemms_kernel(
    const unsigned char* __restrict__ A8, const unsigned char* __restrict__ B8,
    unsigned short* __restrict__ wkt_b,
    const unsigned short* __restrict__ Qb, const unsigned short* __restrict__ WQb,
    unsigned short* __restrict__ qproj_b,
    const float* __restrict__ H, const float* __restrict__ wql,
    float* __restrict__ kv)
{
    __shared__ __align__(16) char smem[33280];
    const int bid = blockIdx.x;
    const int tid = threadIdx.x;
    const int wid = tid >> 6;
    const int lane = tid & 63;
    const int quad = lane >> 4;
    const int l16 = lane & 15;

    if (bid < 1024) {
        // ---- fp8 GEMM: wkt = bf16(fast_tanh((H8 @ WK8^T)/512)), 16384x1024 ---
        unsigned char* As = (unsigned char*)smem;           // 2 x 8 KB
        unsigned char* Bs = (unsigned char*)smem + 16384;   // 2 x 8 KB
        const int m0 = (bid & 127) * 128;   // m-fast grid
        const int n0 = (bid >> 7) * 128;
        const int wm = (wid >> 1) * 64;
        const int wn = (wid & 1) * 64;
        const int stA = wm >> 4;
        const int stB = wn >> 4;
        const int st = wid;
        const int cl = lane * 16;

        f32x4 acc[4][4] = {};
        const unsigned char* Ab = A8 + ((size_t)(m0 >> 4) * 16) * 1024;
        const unsigned char* Bb = B8 + ((size_t)(n0 >> 4) * 16) * 1024;

        auto stage = [&](int buf, int kb) {
            async16(&As[buf * 8192 + tid * 16],        Ab + ((size_t)st * 16 + kb) * 1024 + cl);
            async16(&As[buf * 8192 + 4096 + tid * 16], Ab + ((size_t)(st + 4) * 16 + kb) * 1024 + cl);
            async16(&Bs[buf * 8192 + tid * 16],        Bb + ((size_t)st * 16 + kb) * 1024 + cl);
            async16(&Bs[buf * 8192 + 4096 + tid * 16], Bb + ((size_t)(st + 4) * 16 + kb) * 1024 + cl);
        };

        stage(0, 0);
        __syncthreads();
        for (int kb = 0; kb < 16; kb++) {
            const int cur = kb & 1;
            if (kb < 15) stage(cur ^ 1, kb + 1);

            lx2 a8[4], b8[4];
#pragma unroll
            for (int mt = 0; mt < 4; mt++)
                a8[mt] = *(const lx2*)&As[cur * 8192 + (stA + mt) * 1024 + lane * 16];
#pragma unroll
            for (int nt = 0; nt < 4; nt++)
                b8[nt] = *(const lx2*)&Bs[cur * 8192 + (stB + nt) * 1024 + lane * 16];
#pragma unroll
            for (int mt = 0; mt < 4; mt++)
#pragma unroll
                for (int nt = 0; nt < 4; nt++) {
                    acc[mt][nt] = __builtin_amdgcn_mfma_f32_16x16x32_fp8_fp8(
                        a8[mt].x, b8[nt].x, acc[mt][nt], 0, 0, 0);
                    acc[mt][nt] = __builtin_amdgcn_mfma_f32_16x16x32_fp8_fp8(
                        a8[mt].y, b8[nt].y, acc[mt][nt], 0, 0, 0);
                }
            __syncthreads();
        }

#pragma unroll
        for (int mt = 0; mt < 4; mt++)
#pragma unroll
            for (int nt = 0; nt < 4; nt++)
#pragma unroll
                for (int r = 0; r < 4; r++) {
                    const int row = m0 + wm + mt * 16 + quad * 4 + r;
                    const int col = n0 + wn + nt * 16 + l16;
                    wkt_b[(size_t)row * 1024 + col] =
                        f2bf(fast_tanh(acc[mt][nt][r] * (1.0f / 512.0f)));
                }
    } else if (bid < 1056) {
        // ---- qproj bf16 GEMM: qproj = Qb @ WQb^T (512 x 1024, K=1024) -------
        unsigned short* As = (unsigned short*)smem;            // 8 KB
        unsigned short* Bs = (unsigned short*)(smem + 8192);   // 8 KB
        const int q = bid - 1024;
        const int m0 = (q & 3) * 128;
        const int n0 = (q >> 2) * 128;
        const int wm = (wid >> 1) * 64;
        const int wn = (wid & 1) * 64;

        f32x4 acc[4][4] = {};
        const int r0 = tid >> 2;
        const int cc0 = (tid & 3) * 8;

        for (int k0 = 0; k0 < 1024; k0 += 32) {
            async16(&As[tid * 8],        Qb  + (size_t)(m0 + r0) * 1024 + k0 + cc0);
            async16(&As[2048 + tid * 8], Qb  + (size_t)(m0 + 64 + r0) * 1024 + k0 + cc0);
            async16(&Bs[tid * 8],        WQb + (size_t)(n0 + r0) * 1024 + k0 + cc0);
            async16(&Bs[2048 + tid * 8], WQb + (size_t)(n0 + 64 + r0) * 1024 + k0 + cc0);
            __syncthreads();

            bf16x8 af[4], bfr[4];
#pragma unroll
            for (int mt = 0; mt < 4; mt++)
                af[mt] = *(const bf16x8*)&As[(wm + mt * 16 + l16) * 32 + quad * 8];
#pragma unroll
            for (int nt = 0; nt < 4; nt++)
                bfr[nt] = *(const bf16x8*)&Bs[(wn + nt * 16 + l16) * 32 + quad * 8];
#pragma unroll
            for (int mt = 0; mt < 4; mt++)
#pragma unroll
                for (int nt = 0; nt < 4; nt++)
                    acc[mt][nt] = __builtin_amdgcn_mfma_f32_16x16x32_bf16(
                        af[mt], bfr[nt], acc[mt][nt], 0, 0, 0);
            __syncthreads();
        }

#pragma unroll
        for (int mt = 0; mt < 4; mt++)
#pragma unroll
            for (int nt = 0; nt < 4; nt++)
#pragma unroll
                for (int r = 0; r < 4; r++) {
                    const int row = m0 + wm + mt * 16 + quad * 4 + r;
                    const int col = n0 + wn + nt * 16 + l16;
                    qproj_b[(size_t)row * 1024 + col] = f2bf(acc[mt][nt][r]);
                }
    } else {
        // ---- kv GEMM: kv[((b*16+z)*32+c)*512+t] = sum_h tanh(H)*wql --------
        unsigned short* Ks = (unsigned short*)smem;             // 16 KB [tl][h]
        float* kvt = (float*)(smem + 16384);                    // 16.9 KB [tl][c] pad
        const int q = bid - 1056;
        const int chunk = q & 127;
        const int z = q >> 7;
        const int b = chunk >> 2;
        const int t0 = (chunk & 3) * 128;

#pragma unroll
        for (int it = 0; it < 8; it++) {
            const int idx = it * 256 + tid;
            const int row = idx >> 4;
            const int c4 = (idx & 15) * 4;
            float4 v = *(const float4*)(H + ((size_t)b * T_LEN + t0 + row) * D_MODEL + z * D_K + c4);
            v = fast_tanh4(v);
            ushort4 o;
            o.x = f2bf(v.x); o.y = f2bf(v.y); o.z = f2bf(v.z); o.w = f2bf(v.w);
            *(ushort4*)&Ks[row * 64 + c4] = o;
        }
        bf16x8 bfr[2][2];
#pragma unroll
        for (int ct = 0; ct < 2; ct++)
#pragma unroll
            for (int kh = 0; kh < 2; kh++)
                bfr[ct][kh] = bf8_from_f32(wql +
                    (size_t)(ct * 16 + l16) * D_MODEL + z * D_K + kh * 32 + quad * 8);
        __syncthreads();

        const int wt = wid * 32;
        f32x4 acc[2][2] = {};
#pragma unroll
        for (int tt = 0; tt < 2; tt++) {
            const bf16x8 a0 = *(const bf16x8*)&Ks[(wt + tt * 16 + l16) * 64 + quad * 8];
            const bf16x8 a1 = *(const bf16x8*)&Ks[(wt + tt * 16 + l16) * 64 + 32 + quad * 8];
#pragma unroll
            for (int ct = 0; ct < 2; ct++) {
                acc[tt][ct] = __builtin_amdgcn_mfma_f32_16x16x32_bf16(a0, bfr[ct][0], acc[tt][ct], 0, 0, 0);
                acc[tt][ct] = __builtin_amdgcn_mfma_f32_16x16x32_bf16(a1, bfr[ct][1], acc[tt][ct], 0, 0, 0);
            }
        }
#pragma unroll
        for (int tt = 0; tt < 2; tt++)
#pragma unroll
            for (int ct = 0; ct < 2; ct++)
#pragma unroll
                for (int r = 0; r < 4; r++)
                    kvt[(wt + tt * 16 + quad * 4 + r) * 33 + ct * 16 + l16] = acc[tt][ct][r];
        __syncthreads();

        float* outb = kv + (((size_t)b * 16 + z) * 32) * 512 + t0;
#pragma unroll
        for (int it = 0; it < 4; it++) {
            const int idx = it * 256 + tid;
            const int c = idx >> 5;
            const int tq = (idx & 31) * 4;
            float4 v = make_float4(kvt[(tq + 0) * 33 + c], kvt[(tq + 1) * 33 + c],
                                   kvt[(tq + 2) * 33 + c], kvt[(tq + 3) * 33 + c]);
            *(float4*)(outb + (size_t)c * 512 + tq) = v;
        }
    }
}

// ================= attn: block per (b,z), 8 waves x 4 c-tiles ===============
// 512 threads, 64 KB LDS, 2 blocks/CU (4 waves/SIMD). Round-5-verified:
// exp2 (Q pre-scaled by log2e), kv prefetch, setprio, race-free partials.
__global__ __launch_bounds__(512, 4) void attn_mfma(
    const unsigned short* __restrict__ qproj, const unsigned short* __restrict__ wkt,
    const float* __restrict__ kv, float* __restrict__ part)
{
    __shared__ unsigned short wkts[512 * 64];   // 64 KB, [t][k] swizzled
    const int z = blockIdx.x;
    const int b = blockIdx.y;
    const int tid = threadIdx.x;
    const int wid = tid >> 6;                   // 0..7
    const int lane = tid & 63;
    const int quad = lane >> 4;
    const int l16 = lane & 15;

    const unsigned short* wb = wkt + (size_t)(b * T_LEN) * D_MODEL + z * D_K;
#pragma unroll
    for (int it = 0; it < 8; it++) {
        const int chunk = it * 512 + tid;
        const int row = chunk >> 3;     // t (0..511)
        const int c = chunk & 7;        // 16B chunk within 128B row
        // inverse-swizzled source: LDS(row,c) holds global chunk (c ^ (row&7))
        async16(&wkts[chunk * 8], wb + (size_t)row * D_MODEL + ((c ^ (row & 7)) * 8));
    }

    bf16x8 af[4][2];
#pragma unroll
    for (int ct = 0; ct < 4; ct++)
#pragma unroll
        for (int kh = 0; kh < 2; kh++)
            af[ct][kh] = *(const bf16x8*)(qproj +
                (size_t)((wid * 4 + ct) * 16 + l16) * D_MODEL + z * D_K + kh * 32 + quad * 8);
    __syncthreads();

    float den[4][4], num[4][4];
#pragma unroll
    for (int ct = 0; ct < 4; ct++)
#pragma unroll
        for (int r = 0; r < 4; r++) { den[ct][r] = 0.f; num[ct][r] = 0.f; }

    // per-lane kv base: kv[((b*16+z)*32 + wid*4 + ct)*512 + nt*16 + l16]
    const float* kvp = kv + (((size_t)b * 16 + z) * 32 + wid * 4) * 512 + l16;
    float kc[4];
#pragma unroll
    for (int ct = 0; ct < 4; ct++) kc[ct] = kvp[ct * 512];

    const int x0 = (quad ^ (l16 & 7)) * 8;        // swizzled read: chunks 0..3
    const int x1 = ((quad ^ 4) ^ (l16 & 7)) * 8;  // swizzled read: chunks 4..7
    for (int nt = 0; nt < 32; nt++) {
        float kn[4];
#pragma unroll
        for (int ct = 0; ct < 4; ct++) kn[ct] = kvp[ct * 512 + (nt + 1) * 16];
        const int rbase = (nt * 16 + l16) * 64;
        const bf16x8 b0 = *(const bf16x8*)&wkts[rbase + x0];
        const bf16x8 b1 = *(const bf16x8*)&wkts[rbase + x1];
        f32x4 a4[4];
        __builtin_amdgcn_s_setprio(1);
#pragma unroll
        for (int ct = 0; ct < 4; ct++) {
            f32x4 a = {};
            a = __builtin_amdgcn_mfma_f32_16x16x32_bf16(af[ct][0], b0, a, 0, 0, 0);
            a = __builtin_amdgcn_mfma_f32_16x16x32_bf16(af[ct][1], b1, a, 0, 0, 0);
            a4[ct] = a;
        }
        __builtin_amdgcn_s_setprio(0);
#pragma unroll
        for (int ct = 0; ct < 4; ct++)
#pragma unroll
            for (int r = 0; r < 4; r++) {
                const float e = exp2_fast(a4[ct][r]);
                den[ct][r] += e;
                num[ct][r] += e * kc[ct];
            }
#pragma unroll
        for (int ct = 0; ct < 4; ct++) kc[ct] = kn[ct];
    }

#pragma unroll
    for (int ct = 0; ct < 4; ct++) {
        float s = 0.f;
#pragma unroll
        for (int r = 0; r < 4; r++) {
            float d = den[ct][r], n = num[ct][r];
#pragma unroll
            for (int off = 1; off < 16; off <<= 1) {
                d += __shfl_xor(d, off, 64);
                n += __shfl_xor(n, off, 64);
            }
            s += n / d;
        }
        s += __shfl_xor(s, 16, 64);
        s += __shfl_xor(s, 32, 64);
        if (lane == 0)
            part[((size_t)(b * N_CLASSES) + wid * 4 + ct) * 16 + z] = s;
    }
}

// ---------------- combine z + apply 1/16 s-mean: out[b,c] -------------------
__global__ __launch_bounds__(256) void attn_reduce(
    const float* __restrict__ part, float* __restrict__ out)
{
    const int i = blockIdx.x * 256 + threadIdx.x;   // bc in [0,1024)
    const float* p = part + (size_t)i * 16;
    float s = 0.f;
#pragma unroll
    for (int zz = 0; zz < 16; zz++) s += p[zz];
    out[i] = s * (1.0f / 16.0f);
}

extern "C" void kernel_launch(void* const* d_in, const int* in_sizes, int n_in,
                              void* d_out, int out_size, void* d_ws, size_t ws_size,
                              hipStream_t stream)
{
    const float* Q  = (const float*)d_in[0];   // (32,16,1024)
    const float* H  = (const float*)d_in[1];   // (32,512,1024)
    const float* ql = (const float*)d_in[2];   // (32,1024)
    const float* WQ = (const float*)d_in[3];   // (1024,1024)
    const float* WK = (const float*)d_in[4];
    const float* WV = (const float*)d_in[5];
    float* out = (float*)d_out;                // (32,32)

    char* ws = (char*)d_ws;
    // Flat layout (no overlays, peak ~101 MB):
    //   0        : Hf8      (16.78 MB)
    //   24MB     : Qb       (1 MB)
    //   25MB     : WQb      (2 MB)
    //   27MB     : qproj_b  (1 MB)
    //   29MB     : part     (64 KB)
    //   30MB     : wqlb f32 (128 KB)
    //   32MB     : wkt_b    (33.5 MB)
    //   64MB     : kv       (33.5 MB)
    //   96MB     : WKf8     (1 MB)
    unsigned char*  Hf8     = (unsigned char*)(ws);
    unsigned short* Qb      = (unsigned short*)(ws + (size_t)25165824);
    unsigned short* WQb     = (unsigned short*)(ws + (size_t)26214400);
    unsigned short* qproj_b = (unsigned short*)(ws + (size_t)28311552);
    float*          part    = (float*)(ws + (size_t)30408704);
    float*          wqlb    = (float*)(ws + (size_t)31457280);
    unsigned short* wkt_b   = (unsigned short*)(ws + (size_t)33554432);
    float*          kv      = (float*)(ws + (size_t)67108864);
    unsigned char*  WKf8    = (unsigned char*)(ws + (size_t)100663296);

    dim3 thr(256);
    // wqlb zero for split-K atomics
    hipMemsetAsync(wqlb, 0, (size_t)N_CLASSES * D_MODEL * sizeof(float), stream);
    // prep: wql (256) + fp8 cvt (4096+256) + bf16 cvt (1536) = 6144 blocks
    prep_kernel<<<dim3(6144), thr, 0, stream>>>(
        H, (int*)Hf8, WK, (int*)WKf8,
        (const float4*)Q, (ushort4*)Qb,
        (const float4*)WQ, (ushort4*)WQb,
        ql, WV, wqlb);
    // gemms: fp8 wkt GEMM (1024) + qproj (32) + kv (2048) = 3104 blocks
    gemms_kernel<<<dim3(3104), thr, 0, stream>>>(
        Hf8, WKf8, wkt_b, Qb, WQb, qproj_b, H, wqlb, kv);
    // fused scores -> exp2 -> num/den partials per (b,c,z)
    attn_mfma<<<dim3(16, 32), dim3(512), 0, stream>>>(qproj_b, wkt_b, kv, part);
    // combine z + 1/16 s-mean
    attn_reduce<<<dim3(4), thr, 0, stream>>>(part, out);
}